// Round 1
// baseline (381.626 us; speedup 1.0000x reference)
//
#include <hip/hip_runtime.h>

#define NB   32
#define CH   64
#define LL   2048
#define OUTC 128

typedef float  f32x4  __attribute__((ext_vector_type(4)));
typedef float  f32x16 __attribute__((ext_vector_type(16)));
typedef short  s16x8  __attribute__((ext_vector_type(8)));
typedef unsigned short u16;

__device__ __forceinline__ u16 f2bf(float f) {
  unsigned int u = __builtin_bit_cast(unsigned int, f);
  u += 0x7FFFu + ((u >> 16) & 1u);           // RNE; inputs are finite, no NaN handling
  return (u16)(u >> 16);
}

__device__ __forceinline__ s16x8 packA(const float* v) {
  s16x8 r;
#pragma unroll
  for (int j = 0; j < 8; ++j) r[j] = (short)f2bf(v[j]);
  return r;
}

// ---------------------------------------------------------------------------
// y_out[n] (64 x 2048, bf16) = A[n] (64 x 2048) * m[n] (2048 x 2048)
// A is fp32 (x) when A_F32, else bf16 (previous y) from workspace.
// One block = 64 x 128 output tile; 4 waves, each 64 x 32 (4 row-frags x 2 col-frags).
// B fragments are loaded straight from global fp32 and converted in-register;
// m has zero reuse so LDS staging is pure overhead.
// ---------------------------------------------------------------------------
template<bool A_F32>
__global__ __launch_bounds__(256)
void prop_gemm(const float* __restrict__ xA, const u16* __restrict__ yA,
               const float* __restrict__ m, u16* __restrict__ yOut)
{
  const int n    = blockIdx.x >> 4;
  const int lt   = blockIdx.x & 15;
  const int tid  = threadIdx.x;
  const int wave = tid >> 6;
  const int lane = tid & 63;
  const int l15  = lane & 15;
  const int g4   = lane >> 4;              // 0..3 : k-group
  const int colb = lt * 128 + wave * 32;   // wave's column base

  // B pointers: frag h reads m[(k0 + g4*8 + j)][colb + h*16 + l15]
  const float* mp0 = m + (size_t)n * LL * LL + (size_t)(g4 * 8) * LL + colb + l15;
  const float* mp1 = mp0 + 16;

  const float* ax = nullptr;
  const u16*   ay = nullptr;
  if (A_F32) ax = xA + (size_t)n * CH * LL + (size_t)l15 * LL + g4 * 8;
  else       ay = yA + (size_t)n * CH * LL + (size_t)l15 * LL + g4 * 8;

  f32x4 acc[4][2];
#pragma unroll
  for (int f = 0; f < 4; ++f)
#pragma unroll
    for (int h = 0; h < 2; ++h)
#pragma unroll
      for (int r = 0; r < 4; ++r) acc[f][h][r] = 0.f;

#pragma unroll 2
  for (int k0 = 0; k0 < LL; k0 += 32) {
    // ---- B fragments (8 strided dword loads each, fp32 -> bf16) ----
    float bv0[8], bv1[8];
#pragma unroll
    for (int j = 0; j < 8; ++j) {
      bv0[j] = mp0[(size_t)(k0 + j) * LL];
      bv1[j] = mp1[(size_t)(k0 + j) * LL];
    }
    s16x8 b0 = packA(bv0);
    s16x8 b1 = packA(bv1);

    // ---- A fragments ----
    s16x8 a[4];
    if (A_F32) {
#pragma unroll
      for (int f = 0; f < 4; ++f) {
        const float* p = ax + (size_t)(f * 16) * LL + k0;
        float av[8];
        *(f32x4*)(av)     = *(const f32x4*)(p);
        *(f32x4*)(av + 4) = *(const f32x4*)(p + 4);
        a[f] = packA(av);
      }
    } else {
#pragma unroll
      for (int f = 0; f < 4; ++f)
        a[f] = *(const s16x8*)(ay + (size_t)(f * 16) * LL + k0);
    }

#pragma unroll
    for (int f = 0; f < 4; ++f) {
      acc[f][0] = __builtin_amdgcn_mfma_f32_16x16x32_bf16(a[f], b0, acc[f][0], 0, 0, 0);
      acc[f][1] = __builtin_amdgcn_mfma_f32_16x16x32_bf16(a[f], b1, acc[f][1], 0, 0, 0);
    }
  }

  // ---- store (C/D: col = lane&15, row = g4*4 + r) ----
  u16* o = yOut + (size_t)n * CH * LL + colb + l15;
#pragma unroll
  for (int f = 0; f < 4; ++f)
#pragma unroll
    for (int r = 0; r < 4; ++r) {
      const int row = f * 16 + g4 * 4 + r;
      o[(size_t)row * LL]      = f2bf(acc[f][0][r]);
      o[(size_t)row * LL + 16] = f2bf(acc[f][1][r]);
    }
}

// ---------------------------------------------------------------------------
// out[n] (128 x 2048, fp32) = W (128 x 192) * cat[n] (192 x 2048) + b
// cat rows: [0,64) = x (fp32), [64,128) = y1 (bf16), [128,192) = y2 (bf16)
// Wave tile: 128 x 32 (8 row-frags x 2 col-frags), K = 192 = 6 chunks of 32.
// ---------------------------------------------------------------------------
__global__ __launch_bounds__(256)
void proj(const float* __restrict__ x, const u16* __restrict__ y1,
          const u16* __restrict__ y2, const float* __restrict__ W,
          const float* __restrict__ bias, float* __restrict__ out)
{
  const int n    = blockIdx.x >> 4;
  const int lt   = blockIdx.x & 15;
  const int tid  = threadIdx.x;
  const int wave = tid >> 6;
  const int lane = tid & 63;
  const int l15  = lane & 15;
  const int g4   = lane >> 4;
  const int colb = lt * 128 + wave * 32;

  f32x4 acc[8][2];
#pragma unroll
  for (int f = 0; f < 8; ++f)
#pragma unroll
    for (int h = 0; h < 2; ++h)
#pragma unroll
      for (int r = 0; r < 4; ++r) acc[f][h][r] = 0.f;

  const size_t cb = (size_t)n * CH * LL + colb + l15;
  const float* xp  = x  + cb + (size_t)(g4 * 8) * LL;
  const u16*   y1p = y1 + cb + (size_t)(g4 * 8) * LL;
  const u16*   y2p = y2 + cb + (size_t)(g4 * 8) * LL;
  const float* wp0 = W + (size_t)l15 * 192 + g4 * 8;

#pragma unroll
  for (int kc = 0; kc < 6; ++kc) {
    const int k0 = kc * 32;
    s16x8 b0, b1;
    if (k0 < 64) {
      float bv0[8], bv1[8];
#pragma unroll
      for (int j = 0; j < 8; ++j) {
        bv0[j] = xp[(size_t)(k0 + j) * LL];
        bv1[j] = xp[(size_t)(k0 + j) * LL + 16];
      }
      b0 = packA(bv0); b1 = packA(bv1);
    } else if (k0 < 128) {
#pragma unroll
      for (int j = 0; j < 8; ++j) {
        b0[j] = (short)y1p[(size_t)(k0 - 64 + j) * LL];
        b1[j] = (short)y1p[(size_t)(k0 - 64 + j) * LL + 16];
      }
    } else {
#pragma unroll
      for (int j = 0; j < 8; ++j) {
        b0[j] = (short)y2p[(size_t)(k0 - 128 + j) * LL];
        b1[j] = (short)y2p[(size_t)(k0 - 128 + j) * LL + 16];
      }
    }

#pragma unroll
    for (int f = 0; f < 8; ++f) {
      const float* wp = wp0 + (size_t)(f * 16) * 192 + k0;
      float av[8];
      *(f32x4*)(av)     = *(const f32x4*)(wp);
      *(f32x4*)(av + 4) = *(const f32x4*)(wp + 4);
      s16x8 af = packA(av);
      acc[f][0] = __builtin_amdgcn_mfma_f32_16x16x32_bf16(af, b0, acc[f][0], 0, 0, 0);
      acc[f][1] = __builtin_amdgcn_mfma_f32_16x16x32_bf16(af, b1, acc[f][1], 0, 0, 0);
    }
  }

  float* op = out + (size_t)n * OUTC * LL + colb + l15;
#pragma unroll
  for (int f = 0; f < 8; ++f)
#pragma unroll
    for (int r = 0; r < 4; ++r) {
      const int row = f * 16 + g4 * 4 + r;
      op[(size_t)row * LL]      = acc[f][0][r] + bias[row];
      op[(size_t)row * LL + 16] = acc[f][1][r] + bias[row];
    }
}

extern "C" void kernel_launch(void* const* d_in, const int* in_sizes, int n_in,
                              void* d_out, int out_size, void* d_ws, size_t ws_size,
                              hipStream_t stream)
{
  const float* x = (const float*)d_in[0];
  const float* m = (const float*)d_in[1];
  const float* W = (const float*)d_in[2];
  const float* b = (const float*)d_in[3];
  float* out = (float*)d_out;

  // workspace: y1 (bf16) then y2 (bf16) : 2 * 32*64*2048*2 B = 16 MiB
  u16* y1 = (u16*)d_ws;
  u16* y2 = y1 + (size_t)NB * CH * LL;

  prop_gemm<true ><<<dim3(NB * 16), dim3(256), 0, stream>>>(x, nullptr, m, y1);
  prop_gemm<false><<<dim3(NB * 16), dim3(256), 0, stream>>>(nullptr, y1, m, y2);
  proj<<<dim3(NB * 16), dim3(256), 0, stream>>>(x, y1, y2, W, b, out);
}

// Round 2
// 309.381 us; speedup vs baseline: 1.2335x; 1.2335x over previous
//
#include <hip/hip_runtime.h>

#define NB   32
#define CH   64
#define LL   2048
#define OUTC 128

typedef float  f32x4  __attribute__((ext_vector_type(4)));
typedef short  s16x8  __attribute__((ext_vector_type(8)));
typedef unsigned short u16;

__device__ __forceinline__ u16 f2bf(float f) {
  unsigned int u = __builtin_bit_cast(unsigned int, f);
  u += 0x7FFFu + ((u >> 16) & 1u);           // RNE
  return (u16)(u >> 16);
}

__device__ __forceinline__ s16x8 pack8(const float* v) {
  s16x8 r;
#pragma unroll
  for (int j = 0; j < 8; ++j) r[j] = (short)f2bf(v[j]);
  return r;
}

// ---------------------------------------------------------------------------
// K0: convert x (fp32 -> bf16) and W (fp32 -> bf16), elementwise, 8 elems/thread
// ---------------------------------------------------------------------------
#define NX (NB * CH * LL)          // 4,194,304
#define NW (OUTC * 3 * CH)         // 24,576
__global__ __launch_bounds__(256)
void cvt_inputs(const float* __restrict__ x, const float* __restrict__ W,
                u16* __restrict__ xb, u16* __restrict__ Wb)
{
  const size_t t8 = ((size_t)blockIdx.x * 256 + threadIdx.x) * 8;
  if (t8 < NX) {
    float v[8];
    *(f32x4*)(v)     = *(const f32x4*)(x + t8);
    *(f32x4*)(v + 4) = *(const f32x4*)(x + t8 + 4);
    *(s16x8*)(xb + t8) = pack8(v);
  } else if (t8 - NX < NW) {
    const size_t w8 = t8 - NX;
    float v[8];
    *(f32x4*)(v)     = *(const f32x4*)(W + w8);
    *(f32x4*)(v + 4) = *(const f32x4*)(W + w8 + 4);
    *(s16x8*)(Wb + w8) = pack8(v);
  }
}

// ---------------------------------------------------------------------------
// K1: y1[n] (64x2048 bf16) = xb[n] (64x2048 bf16) * m[n] (2048x2048 fp32)
//     ALSO writes mP: m repacked as bf16 B-fragments:
//     frag_index = ((n*64 + kb)*2048 + col)*4 + g4, 8 bf16 (16B) each,
//     holding m[kb*32 + g4*8 + j][col], j=0..7.
// Block: 64x128 tile, 4 waves of 64x32. Hand 2-deep register pipeline.
// ---------------------------------------------------------------------------
__global__ __launch_bounds__(256, 2)
void prop1_pack(const u16* __restrict__ xb, const float* __restrict__ m,
                u16* __restrict__ y1, u16* __restrict__ mP)
{
  const int n    = blockIdx.x >> 4;
  const int lt   = blockIdx.x & 15;
  const int tid  = threadIdx.x;
  const int wave = tid >> 6;
  const int lane = tid & 63;
  const int l15  = lane & 15;
  const int g4   = lane >> 4;
  const int colb = lt * 128 + wave * 32;

  const float* mp = m  + (size_t)n * LL * LL + (size_t)(g4 * 8) * LL + colb + l15;
  const u16*   ap = xb + (size_t)n * CH * LL + (size_t)l15 * LL + g4 * 8;
  u16* q0 = mP + (((size_t)n * 64 * LL + colb + l15) * 4 + g4) * 8; // + kb*65536, h*512
  u16* o  = y1 + (size_t)n * CH * LL + colb + l15;

  f32x4 acc[4][2];
#pragma unroll
  for (int f = 0; f < 4; ++f)
#pragma unroll
    for (int h = 0; h < 2; ++h)
#pragma unroll
      for (int r = 0; r < 4; ++r) acc[f][h][r] = 0.f;

  float bA0[8], bA1[8], bB0[8], bB1[8];
  s16x8 aA[4], aB[4];

#define K1_LOAD(B0, B1, AV, KB)                                              \
  {                                                                          \
    const float* _mp = mp + (size_t)(KB) * 32 * LL;                          \
    _Pragma("unroll") for (int j = 0; j < 8; ++j) {                          \
      B0[j] = _mp[(size_t)j * LL];                                           \
      B1[j] = _mp[(size_t)j * LL + 16];                                      \
    }                                                                        \
    const u16* _ap = ap + (KB) * 32;                                         \
    _Pragma("unroll") for (int f = 0; f < 4; ++f)                            \
      AV[f] = *(const s16x8*)(_ap + (size_t)(f * 16) * LL);                  \
  }

#define K1_COMP(B0, B1, AV, KB)                                              \
  {                                                                          \
    s16x8 _b0 = pack8(B0), _b1 = pack8(B1);                                  \
    u16* _q = q0 + (size_t)(KB) * 65536;                                     \
    *(s16x8*)(_q)       = _b0;                                               \
    *(s16x8*)(_q + 512) = _b1;                                               \
    _Pragma("unroll") for (int f = 0; f < 4; ++f) {                          \
      acc[f][0] = __builtin_amdgcn_mfma_f32_16x16x32_bf16(AV[f], _b0, acc[f][0], 0, 0, 0); \
      acc[f][1] = __builtin_amdgcn_mfma_f32_16x16x32_bf16(AV[f], _b1, acc[f][1], 0, 0, 0); \
    }                                                                        \
  }

  K1_LOAD(bA0, bA1, aA, 0)
#pragma unroll 1
  for (int kb = 0; kb < 64; kb += 2) {
    K1_LOAD(bB0, bB1, aB, kb + 1)
    K1_COMP(bA0, bA1, aA, kb)
    if (kb + 2 < 64) K1_LOAD(bA0, bA1, aA, kb + 2)
    K1_COMP(bB0, bB1, aB, kb + 1)
  }

#pragma unroll
  for (int f = 0; f < 4; ++f)
#pragma unroll
    for (int r = 0; r < 4; ++r) {
      const int row = f * 16 + g4 * 4 + r;
      o[(size_t)row * LL]      = f2bf(acc[f][0][r]);
      o[(size_t)row * LL + 16] = f2bf(acc[f][1][r]);
    }
}

// ---------------------------------------------------------------------------
// K2: y2[n] = y1[n] * m[n], reading mP (pre-packed bf16 fragments).
// All loads contiguous 16B. Hand 2-deep register pipeline.
// ---------------------------------------------------------------------------
__global__ __launch_bounds__(256, 2)
void prop2(const u16* __restrict__ y1, const u16* __restrict__ mP,
           u16* __restrict__ y2)
{
  const int n    = blockIdx.x >> 4;
  const int lt   = blockIdx.x & 15;
  const int tid  = threadIdx.x;
  const int wave = tid >> 6;
  const int lane = tid & 63;
  const int l15  = lane & 15;
  const int g4   = lane >> 4;
  const int colb = lt * 128 + wave * 32;

  const u16* mq = mP + (((size_t)n * 64 * LL + colb + l15) * 4 + g4) * 8;
  const u16* ap = y1 + (size_t)n * CH * LL + (size_t)l15 * LL + g4 * 8;
  u16* o = y2 + (size_t)n * CH * LL + colb + l15;

  f32x4 acc[4][2];
#pragma unroll
  for (int f = 0; f < 4; ++f)
#pragma unroll
    for (int h = 0; h < 2; ++h)
#pragma unroll
      for (int r = 0; r < 4; ++r) acc[f][h][r] = 0.f;

  s16x8 bA0, bA1, bB0, bB1, aA[4], aB[4];

#define K2_LOAD(B0, B1, AV, KB)                                              \
  {                                                                          \
    const u16* _mq = mq + (size_t)(KB) * 65536;                              \
    B0 = *(const s16x8*)(_mq);                                               \
    B1 = *(const s16x8*)(_mq + 512);                                         \
    const u16* _ap = ap + (KB) * 32;                                         \
    _Pragma("unroll") for (int f = 0; f < 4; ++f)                            \
      AV[f] = *(const s16x8*)(_ap + (size_t)(f * 16) * LL);                  \
  }

#define K2_COMP(B0, B1, AV)                                                  \
  _Pragma("unroll") for (int f = 0; f < 4; ++f) {                            \
    acc[f][0] = __builtin_amdgcn_mfma_f32_16x16x32_bf16(AV[f], B0, acc[f][0], 0, 0, 0); \
    acc[f][1] = __builtin_amdgcn_mfma_f32_16x16x32_bf16(AV[f], B1, acc[f][1], 0, 0, 0); \
  }

  K2_LOAD(bA0, bA1, aA, 0)
#pragma unroll 1
  for (int kb = 0; kb < 64; kb += 2) {
    K2_LOAD(bB0, bB1, aB, kb + 1)
    K2_COMP(bA0, bA1, aA)
    if (kb + 2 < 64) K2_LOAD(bA0, bA1, aA, kb + 2)
    K2_COMP(bB0, bB1, aB)
  }

#pragma unroll
  for (int f = 0; f < 4; ++f)
#pragma unroll
    for (int r = 0; r < 4; ++r) {
      const int row = f * 16 + g4 * 4 + r;
      o[(size_t)row * LL]      = f2bf(acc[f][0][r]);
      o[(size_t)row * LL + 16] = f2bf(acc[f][1][r]);
    }
}

// ---------------------------------------------------------------------------
// K3: out[n] (128x2048 fp32) = Wb (128x192 bf16) * cat[n] (192x2048 bf16) + b
// cat rows: [0,64)=xb, [64,128)=y1, [128,192)=y2. Wave: 128x32, K=6x32.
// ---------------------------------------------------------------------------
__global__ __launch_bounds__(256)
void proj(const u16* __restrict__ xb, const u16* __restrict__ y1,
          const u16* __restrict__ y2, const u16* __restrict__ Wb,
          const float* __restrict__ bias, float* __restrict__ out)
{
  const int n    = blockIdx.x >> 4;
  const int lt   = blockIdx.x & 15;
  const int tid  = threadIdx.x;
  const int wave = tid >> 6;
  const int lane = tid & 63;
  const int l15  = lane & 15;
  const int g4   = lane >> 4;
  const int colb = lt * 128 + wave * 32;

  f32x4 acc[8][2];
#pragma unroll
  for (int f = 0; f < 8; ++f)
#pragma unroll
    for (int h = 0; h < 2; ++h)
#pragma unroll
      for (int r = 0; r < 4; ++r) acc[f][h][r] = 0.f;

  const size_t cb = (size_t)n * CH * LL + colb + l15;
  const u16* xp  = xb + cb + (size_t)(g4 * 8) * LL;
  const u16* y1p = y1 + cb + (size_t)(g4 * 8) * LL;
  const u16* y2p = y2 + cb + (size_t)(g4 * 8) * LL;
  const u16* wq  = Wb + (size_t)l15 * 192 + g4 * 8;

#pragma unroll
  for (int kc = 0; kc < 6; ++kc) {
    const int k0 = kc * 32;
    s16x8 b0, b1;
    const u16* src = (k0 < 64) ? (xp + (size_t)k0 * LL)
                   : (k0 < 128) ? (y1p + (size_t)(k0 - 64) * LL)
                                : (y2p + (size_t)(k0 - 128) * LL);
#pragma unroll
    for (int j = 0; j < 8; ++j) {
      b0[j] = (short)src[(size_t)j * LL];
      b1[j] = (short)src[(size_t)j * LL + 16];
    }

#pragma unroll
    for (int f = 0; f < 8; ++f) {
      s16x8 af = *(const s16x8*)(wq + (size_t)(f * 16) * 192 + k0);
      acc[f][0] = __builtin_amdgcn_mfma_f32_16x16x32_bf16(af, b0, acc[f][0], 0, 0, 0);
      acc[f][1] = __builtin_amdgcn_mfma_f32_16x16x32_bf16(af, b1, acc[f][1], 0, 0, 0);
    }
  }

  float* op = out + (size_t)n * OUTC * LL + colb + l15;
#pragma unroll
  for (int f = 0; f < 8; ++f)
#pragma unroll
    for (int r = 0; r < 4; ++r) {
      const int row = f * 16 + g4 * 4 + r;
      op[(size_t)row * LL]      = acc[f][0][r] + bias[row];
      op[(size_t)row * LL + 16] = acc[f][1][r] + bias[row];
    }
}

extern "C" void kernel_launch(void* const* d_in, const int* in_sizes, int n_in,
                              void* d_out, int out_size, void* d_ws, size_t ws_size,
                              hipStream_t stream)
{
  const float* x = (const float*)d_in[0];
  const float* m = (const float*)d_in[1];
  const float* W = (const float*)d_in[2];
  const float* b = (const float*)d_in[3];
  float* out = (float*)d_out;

  // workspace layout (u16 elems): y1 | y2 | xb | Wb | mP
  u16* y1 = (u16*)d_ws;                          //  8 MiB
  u16* y2 = y1 + (size_t)NB * CH * LL;           //  8 MiB
  u16* xb = y2 + (size_t)NB * CH * LL;           //  8 MiB
  u16* Wb = xb + (size_t)NB * CH * LL;           // 48 KiB
  u16* mP = (u16*)((char*)d_ws + (25u << 20));   // 256 MiB, 1 MiB-aligned

  cvt_inputs<<<dim3(2060), dim3(256), 0, stream>>>(x, W, xb, Wb);
  prop1_pack<<<dim3(NB * 16), dim3(256), 0, stream>>>(xb, m, y1, mP);
  prop2<<<dim3(NB * 16), dim3(256), 0, stream>>>(y1, mP, y2);
  proj<<<dim3(NB * 16), dim3(256), 0, stream>>>(xb, y1, y2, Wb, b, out);
}